// Round 1
// baseline (766.745 us; speedup 1.0000x reference)
//
#include <hip/hip_runtime.h>
#include <math.h>

#define BB 32
#define CC 256
#define HW 16384          // 128*128
#define BC (BB*CC)        // 8192

// ws layout (floats):
// [0, 8192)        pooled[b*256+c]
// [8192, 24576)    entro[hw] accumulator (sum over b of xn/32)
// [24576]          sig_sum accumulator

__global__ __launch_bounds__(256) void pool_kernel(const float* __restrict__ x,
                                                   float* __restrict__ ws) {
    const int bc = blockIdx.x;
    const int t  = threadIdx.x;
    const float4* xv = (const float4*)x + (size_t)bc * (HW / 4);
    float s = 0.f;
#pragma unroll
    for (int i = 0; i < 16; ++i) {
        float4 v = xv[t + i * 256];
        s += v.x + v.y + v.z + v.w;
    }
    for (int o = 32; o > 0; o >>= 1) s += __shfl_down(s, o);
    __shared__ float part[4];
    if ((t & 63) == 0) part[t >> 6] = s;
    __syncthreads();
    if (t == 0) {
        float tot = part[0] + part[1] + part[2] + part[3];
        ws[bc] = tot * (1.0f / HW);
    }
    // zero the downstream accumulators (safe: consumed only by later kernels)
    int tid = bc * 256 + t;
    if (tid < HW) ws[BC + tid] = 0.f;
    if (tid == 0) ws[BC + HW] = 0.f;
}

__global__ __launch_bounds__(256) void xn_kernel(const float* __restrict__ x,
                                                 float* __restrict__ ws) {
    const int b     = blockIdx.x >> 4;   // 16 blocks per batch image
    const int chunk = blockIdx.x & 15;
    const int t     = threadIdx.x;

    __shared__ float spool[CC];
    spool[t] = ws[b * CC + t];
    __syncthreads();

    const float4* xv = (const float4*)x;
    const size_t base = (size_t)b * CC * (HW / 4) + (size_t)chunk * 256 + t;

    float ax = 0.f, ay = 0.f, az = 0.f, aw = 0.f;
#pragma unroll 4
    for (int c = 0; c < CC; ++c) {
        float4 v = xv[base + (size_t)c * (HW / 4)];
        float p = spool[c];
        ax += v.x * p; ay += v.y * p; az += v.z * p; aw += v.w * p;
    }
    const float inv_c = 1.0f / CC;
    float xn0 = ax * inv_c, xn1 = ay * inv_c, xn2 = az * inv_c, xn3 = aw * inv_c;

    // accumulate entro[hw] = mean over b of xn
    float* entro = ws + BC;
    const int hw = (chunk * 256 + t) * 4;
    const float inv_b = 1.0f / BB;
    atomicAdd(&entro[hw + 0], xn0 * inv_b);
    atomicAdd(&entro[hw + 1], xn1 * inv_b);
    atomicAdd(&entro[hw + 2], xn2 * inv_b);
    atomicAdd(&entro[hw + 3], xn3 * inv_b);

    // sigmoid partial sum
    float sg = 1.f / (1.f + expf(-xn0)) + 1.f / (1.f + expf(-xn1)) +
               1.f / (1.f + expf(-xn2)) + 1.f / (1.f + expf(-xn3));
    for (int o = 32; o > 0; o >>= 1) sg += __shfl_down(sg, o);
    __shared__ float part[4];
    if ((t & 63) == 0) part[t >> 6] = sg;
    __syncthreads();
    if (t == 0) {
        float tot = part[0] + part[1] + part[2] + part[3];
        atomicAdd(&ws[BC + HW], tot);
    }
}

__global__ __launch_bounds__(256) void finalize_kernel(const float* __restrict__ ws,
                                                       float* __restrict__ out) {
    const int t = threadIdx.x;
    const float* entro = ws + BC;

    float lmin = INFINITY, lmax = -INFINITY;
#pragma unroll
    for (int i = 0; i < 64; ++i) {
        float v = entro[t + i * 256];
        lmin = fminf(lmin, v);
        lmax = fmaxf(lmax, v);
    }
    for (int o = 32; o > 0; o >>= 1) {
        lmin = fminf(lmin, __shfl_down(lmin, o));
        lmax = fmaxf(lmax, __shfl_down(lmax, o));
    }
    __shared__ float smin[4], smax[4];
    __shared__ float bmin, bmax;
    if ((t & 63) == 0) { smin[t >> 6] = lmin; smax[t >> 6] = lmax; }
    __syncthreads();
    if (t == 0) {
        bmin = fminf(fminf(smin[0], smin[1]), fminf(smin[2], smin[3]));
        bmax = fmaxf(fmaxf(smax[0], smax[1]), fmaxf(smax[2], smax[3]));
    }
    __shared__ unsigned int hist[256];
    hist[t] = 0u;
    __syncthreads();

    const float emin = bmin, emax = bmax;
    const float scale = 256.0f / (emax - emin);
#pragma unroll
    for (int i = 0; i < 64; ++i) {
        float v = entro[t + i * 256];
        int idx = (int)floorf((v - emin) * scale);
        idx = idx < 0 ? 0 : (idx > 255 ? 255 : idx);
        atomicAdd(&hist[idx], 1u);
    }
    __syncthreads();

    const unsigned int h = hist[t];
    const float his = (float)h * (1.0f / HW);
    float term = (h > 0u) ? his * (-logf(his + 1e-8f)) : 0.f;
    float nzf  = (h > 0u) ? 1.f : 0.f;
    for (int o = 32; o > 0; o >>= 1) {
        term += __shfl_down(term, o);
        nzf  += __shfl_down(nzf, o);
    }
    __shared__ float sterm[4], snz[4];
    if ((t & 63) == 0) { sterm[t >> 6] = term; snz[t >> 6] = nzf; }
    __syncthreads();
    if (t == 0) {
        float ent = sterm[0] + sterm[1] + sterm[2] + sterm[3];
        float nz  = snz[0] + snz[1] + snz[2] + snz[3];
        float sig = ws[BC + HW] * (1.0f / ((float)BB * (float)HW));
        out[0] = sig + (ent / nz) * 10.0f;
    }
}

extern "C" void kernel_launch(void* const* d_in, const int* in_sizes, int n_in,
                              void* d_out, int out_size, void* d_ws, size_t ws_size,
                              hipStream_t stream) {
    const float* x = (const float*)d_in[0];
    float* out = (float*)d_out;
    float* ws  = (float*)d_ws;

    pool_kernel<<<BC, 256, 0, stream>>>(x, ws);
    xn_kernel<<<BB * 16, 256, 0, stream>>>(x, ws);
    finalize_kernel<<<1, 256, 0, stream>>>(ws, out);
}